// Round 1
// baseline (54.959 us; speedup 1.0000x reference)
//
#include <hip/hip_runtime.h>
#include <math.h>

// Problem sizes (fixed by reference setup_inputs)
#define NP      (128 * 196)   // 25088 patches
#define PATCH   768           // elements per patch
#define ND      128           // contrastive N
#define DD      256           // contrastive D
#define TEMP_INV 10.0f        // 1 / 0.1
#define COS_EPS_F 1e-8f

#define NB_R 1024             // recon blocks (4 waves each -> 4096 waves)
#define NB_C 32               // contrastive blocks (4 rows each -> 128 rows)

__device__ __forceinline__ float wave_sum(float v) {
#pragma unroll
    for (int o = 32; o; o >>= 1) v += __shfl_xor(v, o);
    return v;
}
__device__ __forceinline__ float wave_max(float v) {
#pragma unroll
    for (int o = 32; o; o >>= 1) v = fmaxf(v, __shfl_xor(v, o));
    return v;
}

// ws layout (floats):
//   [0        .. NB_R)        per-block weighted-loss partial
//   [NB_R     .. 2*NB_R)      per-block mask-sum partial
//   [2*NB_R   .. 2*NB_R+128)  per-row contrastive contribution (lse_i - S_ii/T)
__global__ __launch_bounds__(256) void partials_kernel(
    const float* __restrict__ preds,   // student_prob [128,256]
    const float* __restrict__ tgts,    // teacher_prob [128,256]
    const float* __restrict__ rt,      // reconstruct_target [B,L,P]
    const float* __restrict__ rp,      // reconstruct_pred   [B,L,P]
    const float* __restrict__ mask,    // [B,L]
    float* __restrict__ ws)
{
    __shared__ float s_red[8];
    __shared__ float4 pn4s[4][DD / 4];   // normalized pred row per wave
    __shared__ float inv_t[ND];

    const int tid  = threadIdx.x;
    const int w    = tid >> 6;
    const int lane = tid & 63;
    const int blk  = blockIdx.x;

    if (blk < NB_R) {
        // ---------------- reconstruction partial sums ----------------
        float acc_l = 0.f, acc_m = 0.f;
        const int gw = blk * 4 + w;          // global wave id, 0..4095
        for (int p = gw; p < NP; p += NB_R * 4) {
            const float4* t4 = (const float4*)(rt + (size_t)p * PATCH);
            const float4* p4 = (const float4*)(rp + (size_t)p * PATCH);
            float4 T[3], Q[3];
#pragma unroll
            for (int q = 0; q < 3; ++q) {
                T[q] = t4[lane + 64 * q];
                Q[q] = p4[lane + 64 * q];
            }
            float s = 0.f, ss = 0.f;
#pragma unroll
            for (int q = 0; q < 3; ++q) {
                s  += T[q].x + T[q].y + T[q].z + T[q].w;
                ss += T[q].x * T[q].x + T[q].y * T[q].y
                    + T[q].z * T[q].z + T[q].w * T[q].w;
            }
            s  = wave_sum(s);
            ss = wave_sum(ss);
            const float mean = s * (1.0f / PATCH);
            const float var  = (ss - s * mean) * (1.0f / (PATCH - 1));
            const float rstd = 1.0f / sqrtf(var + 1e-6f);

            float l = 0.f;
#pragma unroll
            for (int q = 0; q < 3; ++q) {
                float dx = Q[q].x - (T[q].x - mean) * rstd;
                float dy = Q[q].y - (T[q].y - mean) * rstd;
                float dz = Q[q].z - (T[q].z - mean) * rstd;
                float dw = Q[q].w - (T[q].w - mean) * rstd;
                l += dx * dx + dy * dy + dz * dz + dw * dw;
            }
            l = wave_sum(l);
            const float mk = mask[p];
            acc_l += (l * (1.0f / PATCH)) * mk;
            acc_m += mk;
        }
        if (lane == 0) { s_red[w] = acc_l; s_red[4 + w] = acc_m; }
        __syncthreads();
        if (tid == 0) {
            float la = 0.f, lm = 0.f;
#pragma unroll
            for (int k = 0; k < 4; ++k) { la += s_red[k]; lm += s_red[4 + k]; }
            ws[blk]        = la;
            ws[NB_R + blk] = lm;
        }
    } else {
        // ---------------- contrastive per-row contributions ----------------
        const int cb = blk - NB_R;       // 0..31
        const int i  = cb * 4 + w;       // row 0..127
        const float4* pg = (const float4*)preds;
        const float4* tg = (const float4*)tgts;

        // inverse norms of all target rows (wave w handles 32 rows)
        for (int r = w * 32; r < w * 32 + 32; ++r) {
            float4 u = tg[r * (DD / 4) + lane];
            float ssq = wave_sum(u.x * u.x + u.y * u.y + u.z * u.z + u.w * u.w);
            if (lane == 0) inv_t[r] = 1.0f / fmaxf(sqrtf(ssq), COS_EPS_F);
        }
        // stage normalized pred row i into LDS
        float4 v = pg[(size_t)i * (DD / 4) + lane];
        float ssp = wave_sum(v.x * v.x + v.y * v.y + v.z * v.z + v.w * v.w);
        float invp = 1.0f / fmaxf(sqrtf(ssp), COS_EPS_F);
        pn4s[w][lane] = make_float4(v.x * invp, v.y * invp, v.z * invp, v.w * invp);
        __syncthreads();

        const int j1 = lane, j2 = lane + 64;
        float d1 = 0.f, d2 = 0.f;
#pragma unroll 4
        for (int k = 0; k < DD / 4; ++k) {
            float4 c = pn4s[w][k];                 // LDS broadcast
            float4 a = tg[j1 * (DD / 4) + k];
            float4 b = tg[j2 * (DD / 4) + k];
            d1 += c.x * a.x + c.y * a.y + c.z * a.z + c.w * a.w;
            d2 += c.x * b.x + c.y * b.y + c.z * b.z + c.w * b.w;
        }
        const float s1 = d1 * inv_t[j1] * TEMP_INV;
        const float s2 = d2 * inv_t[j2] * TEMP_INV;
        float m = wave_max(fmaxf(s1, s2));
        float sum = wave_sum(expf(s1 - m) + expf(s2 - m));
        const float lse = m + logf(sum);
        const float pos = (i < 64) ? __shfl(s1, i) : __shfl(s2, i - 64);
        if (lane == 0) ws[2 * NB_R + i] = lse - pos;
    }
}

__global__ __launch_bounds__(256) void finalize_kernel(
    const float* __restrict__ ws, float* __restrict__ out)
{
    __shared__ float s_red[12];
    const int tid = threadIdx.x, w = tid >> 6, lane = tid & 63;
    float a = 0.f, b = 0.f, c = 0.f;
    for (int i = tid; i < NB_R; i += 256) {
        a += ws[i];
        b += ws[NB_R + i];
    }
    if (tid < ND) c = ws[2 * NB_R + tid];
    a = wave_sum(a); b = wave_sum(b); c = wave_sum(c);
    if (lane == 0) { s_red[w] = a; s_red[4 + w] = b; s_red[8 + w] = c; }
    __syncthreads();
    if (tid == 0) {
        float la = 0.f, lb = 0.f, lc = 0.f;
#pragma unroll
        for (int k = 0; k < 4; ++k) {
            la += s_red[k]; lb += s_red[4 + k]; lc += s_red[8 + k];
        }
        const float recon = la / lb;
        const float contr = lc / (float)ND;
        out[0] = recon;
        out[1] = contr;
        out[2] = recon + contr;
    }
}

extern "C" void kernel_launch(void* const* d_in, const int* in_sizes, int n_in,
                              void* d_out, int out_size, void* d_ws, size_t ws_size,
                              hipStream_t stream) {
    const float* student = (const float*)d_in[0];
    const float* teacher = (const float*)d_in[1];
    const float* rt      = (const float*)d_in[2];
    const float* rp      = (const float*)d_in[3];
    const float* mask    = (const float*)d_in[4];
    float* ws  = (float*)d_ws;
    float* out = (float*)d_out;

    hipLaunchKernelGGL(partials_kernel, dim3(NB_R + NB_C), dim3(256), 0, stream,
                       student, teacher, rt, rp, mask, ws);
    hipLaunchKernelGGL(finalize_kernel, dim3(1), dim3(256), 0, stream, ws, out);
}

// Round 2
// 46.687 us; speedup vs baseline: 1.1772x; 1.1772x over previous
//
#include <hip/hip_runtime.h>
#include <math.h>

// Problem sizes (fixed by reference setup_inputs)
#define NP      (128 * 196)   // 25088 patches
#define PATCH   768           // elements per patch
#define ND      128           // contrastive N
#define DD      256           // contrastive D
#define TEMP_INV 10.0f        // 1 / 0.1
#define COS_EPS_F 1e-8f

#define NB_R 3136             // recon blocks: 4 waves each -> 12544 waves, 2 patches/wave
#define NB_C 32               // contrastive blocks (4 rows each -> 128 rows)

__device__ __forceinline__ float wave_sum(float v) {
#pragma unroll
    for (int o = 32; o; o >>= 1) v += __shfl_xor(v, o);
    return v;
}
__device__ __forceinline__ float wave_max(float v) {
#pragma unroll
    for (int o = 32; o; o >>= 1) v = fmaxf(v, __shfl_xor(v, o));
    return v;
}
__device__ __forceinline__ float dot4(float4 a, float4 b) {
    return a.x * b.x + a.y * b.y + a.z * b.z + a.w * b.w;
}

// ws layout (floats):
//   [0        .. NB_R)        per-block weighted-loss partial
//   [NB_R     .. 2*NB_R)      per-block mask-sum partial
//   [2*NB_R   .. 2*NB_R+128)  per-row contrastive contribution (lse_i - S_ii/T)
__global__ __launch_bounds__(256) void partials_kernel(
    const float* __restrict__ preds,   // student_prob [128,256]
    const float* __restrict__ tgts,    // teacher_prob [128,256]
    const float* __restrict__ rt,      // reconstruct_target [B,L,P]
    const float* __restrict__ rp,      // reconstruct_pred   [B,L,P]
    const float* __restrict__ mask,    // [B,L]
    float* __restrict__ ws)
{
    __shared__ float s_red[8];
    __shared__ float4 pn4s[4][DD / 4];   // normalized pred row per wave

    const int tid  = threadIdx.x;
    const int w    = tid >> 6;
    const int lane = tid & 63;
    const int blk  = blockIdx.x;

    if (blk < NB_R) {
        // ---------------- reconstruction partial sums ----------------
        // Each wave owns exactly 2 adjacent patches; all 12 float4 loads
        // issued before any reduction (single fused reduction phase).
        const int gw = blk * 4 + w;              // 0..12543
        const int p0 = gw * 2;
        const float4* t4 = (const float4*)(rt + (size_t)p0 * PATCH);
        const float4* q4 = (const float4*)(rp + (size_t)p0 * PATCH);

        float4 T[2][3], Q[2][3];
#pragma unroll
        for (int pp = 0; pp < 2; ++pp)
#pragma unroll
            for (int q = 0; q < 3; ++q) {
                T[pp][q] = t4[pp * (PATCH / 4) + lane + 64 * q];
                Q[pp][q] = q4[pp * (PATCH / 4) + lane + 64 * q];
            }
        const float m0 = mask[p0], m1 = mask[p0 + 1];

        // 5 linear sums per patch: s=Σt ss=Σt² sp=Σq spp=Σq² spt=Σqt
        float s[2], ss[2], sp[2], spp[2], spt[2];
#pragma unroll
        for (int pp = 0; pp < 2; ++pp) {
            s[pp] = ss[pp] = sp[pp] = spp[pp] = spt[pp] = 0.f;
#pragma unroll
            for (int q = 0; q < 3; ++q) {
                float4 t = T[pp][q], p = Q[pp][q];
                s[pp]   += t.x + t.y + t.z + t.w;
                ss[pp]  += dot4(t, t);
                sp[pp]  += p.x + p.y + p.z + p.w;
                spp[pp] += dot4(p, p);
                spt[pp] += dot4(p, t);
            }
        }
        // one butterfly over all 10 values (10 independent chains -> ILP)
#pragma unroll
        for (int o = 32; o; o >>= 1) {
#pragma unroll
            for (int pp = 0; pp < 2; ++pp) {
                s[pp]   += __shfl_xor(s[pp], o);
                ss[pp]  += __shfl_xor(ss[pp], o);
                sp[pp]  += __shfl_xor(sp[pp], o);
                spp[pp] += __shfl_xor(spp[pp], o);
                spt[pp] += __shfl_xor(spt[pp], o);
            }
        }
        float acc_l = 0.f;
#pragma unroll
        for (int pp = 0; pp < 2; ++pp) {
            const float mean = s[pp] * (1.0f / PATCH);
            const float cvar = ss[pp] - s[pp] * mean;            // Σ(t-mean)²
            const float var  = cvar * (1.0f / (PATCH - 1));
            const float rstd = 1.0f / sqrtf(var + 1e-6f);
            // Σ(q - (t-mean)·rstd)² = spp - 2·rstd·(spt - mean·sp) + rstd²·cvar
            const float lsum = spp[pp] - 2.f * rstd * (spt[pp] - mean * sp[pp])
                             + rstd * rstd * cvar;
            acc_l += lsum * (1.0f / PATCH) * (pp ? m1 : m0);
        }
        const float acc_m = m0 + m1;

        if (lane == 0) { s_red[w] = acc_l; s_red[4 + w] = acc_m; }
        __syncthreads();
        if (tid == 0) {
            float la = 0.f, lm = 0.f;
#pragma unroll
            for (int k = 0; k < 4; ++k) { la += s_red[k]; lm += s_red[4 + k]; }
            ws[blk]        = la;
            ws[NB_R + blk] = lm;
        }
    } else {
        // ---------------- contrastive per-row contributions ----------------
        const int cb = blk - NB_R;       // 0..31
        const int i  = cb * 4 + w;       // row 0..127
        const float4* pg = (const float4*)preds;
        const float4* tg = (const float4*)tgts;

        // stage normalized pred row i into LDS (wave-local)
        float4 v = pg[(size_t)i * (DD / 4) + lane];
        float ssp = wave_sum(dot4(v, v));
        float invp = 1.0f / fmaxf(sqrtf(ssp), COS_EPS_F);
        pn4s[w][lane] = make_float4(v.x * invp, v.y * invp, v.z * invp, v.w * invp);
        __syncthreads();

        // lane j reads full teacher row j: accumulate dot AND row norm inline
        const int j1 = lane, j2 = lane + 64;
        float d1 = 0.f, d2 = 0.f, n1 = 0.f, n2 = 0.f;
#pragma unroll 8
        for (int k = 0; k < DD / 4; ++k) {
            float4 c = pn4s[w][k];                 // LDS broadcast
            float4 a = tg[j1 * (DD / 4) + k];
            float4 b = tg[j2 * (DD / 4) + k];
            d1 += dot4(c, a);  n1 += dot4(a, a);
            d2 += dot4(c, b);  n2 += dot4(b, b);
        }
        const float s1 = d1 * (1.0f / fmaxf(sqrtf(n1), COS_EPS_F)) * TEMP_INV;
        const float s2 = d2 * (1.0f / fmaxf(sqrtf(n2), COS_EPS_F)) * TEMP_INV;
        float m = wave_max(fmaxf(s1, s2));
        float sum = wave_sum(expf(s1 - m) + expf(s2 - m));
        const float lse = m + logf(sum);
        const float pos = (i < 64) ? __shfl(s1, i) : __shfl(s2, i - 64);
        if (lane == 0) ws[2 * NB_R + i] = lse - pos;
    }
}

__global__ __launch_bounds__(256) void finalize_kernel(
    const float* __restrict__ ws, float* __restrict__ out)
{
    __shared__ float s_red[12];
    const int tid = threadIdx.x, w = tid >> 6, lane = tid & 63;
    float a = 0.f, b = 0.f, c = 0.f;
    for (int i = tid; i < NB_R; i += 256) {
        a += ws[i];
        b += ws[NB_R + i];
    }
    if (tid < ND) c = ws[2 * NB_R + tid];
    a = wave_sum(a); b = wave_sum(b); c = wave_sum(c);
    if (lane == 0) { s_red[w] = a; s_red[4 + w] = b; s_red[8 + w] = c; }
    __syncthreads();
    if (tid == 0) {
        float la = 0.f, lb = 0.f, lc = 0.f;
#pragma unroll
        for (int k = 0; k < 4; ++k) {
            la += s_red[k]; lb += s_red[4 + k]; lc += s_red[8 + k];
        }
        const float recon = la / lb;
        const float contr = lc / (float)ND;
        out[0] = recon;
        out[1] = contr;
        out[2] = recon + contr;
    }
}

extern "C" void kernel_launch(void* const* d_in, const int* in_sizes, int n_in,
                              void* d_out, int out_size, void* d_ws, size_t ws_size,
                              hipStream_t stream) {
    const float* student = (const float*)d_in[0];
    const float* teacher = (const float*)d_in[1];
    const float* rt      = (const float*)d_in[2];
    const float* rp      = (const float*)d_in[3];
    const float* mask    = (const float*)d_in[4];
    float* ws  = (float*)d_ws;
    float* out = (float*)d_out;

    hipLaunchKernelGGL(partials_kernel, dim3(NB_R + NB_C), dim3(256), 0, stream,
                       student, teacher, rt, rp, mask, ws);
    hipLaunchKernelGGL(finalize_kernel, dim3(1), dim3(256), 0, stream, ws, out);
}